// Round 10
// baseline (97.243 us; speedup 1.0000x reference)
//
#include <hip/hip_runtime.h>
#include <math.h>

#define B   4
#define NF  4096
#define FM  32
#define H   128
#define NC  256
#define ROW (FM * H)      // 4096 floats per (b,n) row
#define RQ  (ROW / 4)     // 1024 float4 per row
#define NT  1024          // threads per block (16 waves)
#define SPT (NF / NT)     // 4 seg values per thread

// One kernel. Block = (pair_rank, b), 1024 threads; processes segments
// ord[pr] and ord[255-pr] (folded size-pairing -> near-constant work).
// 512 blocks = 2 blocks/CU = 32 waves/CU (VGPR<=64 via one float4/row/thread
// and launch_bounds(1024,8)). Preamble per block (seg tiny/L2-resident):
// histogram, rank by size, atomic-cursor compaction. Stream: 4-row batches,
// ONE barrier + one float4 LDS broadcast per batch, online softmax; every
// x element read exactly once across the grid.
__global__ __launch_bounds__(NT, 8) void k_fused(const float* __restrict__ x,
                                                 const float* __restrict__ W,
                                                 const float* __restrict__ bias,
                                                 const int* __restrict__ seg,
                                                 float* __restrict__ out) {
    __shared__ __align__(16) int cnt[NC];
    __shared__ int    list[NF];       // 16 KB member list of current segment
    __shared__ float4 red4[2][16];    // [parity][wave] -> 4 row-partials
    __shared__ int    s_c[2];
    __shared__ int    s_cur;

    const int t    = threadIdx.x;
    const int wid  = t >> 6;         // 0..15
    const int lane = t & 63;
    const int pr   = blockIdx.x >> 2;     // pair rank 0..127
    const int b    = blockIdx.x & 3;

    // ---- histogram of segment sizes (thread t owns ints [4t, 4t+4)) ----
    int sv[SPT];
    if (t < NC) cnt[t] = 0;
    __syncthreads();
    {
        const int4 v = ((const int4*)seg)[t];
        sv[0] = v.x; sv[1] = v.y; sv[2] = v.z; sv[3] = v.w;
#pragma unroll
        for (int k = 0; k < SPT; ++k)
            atomicAdd(&cnt[sv[k]], 1);
    }
    __syncthreads();

    // ---- rank segment t (t<256) by descending count, ties by id ----
    if (t < NC) {
        const int my = cnt[t];
        int r = 0;
        const int4* c4 = (const int4*)cnt;   // broadcast reads
#pragma unroll 16
        for (int j = 0; j < 64; ++j) {
            const int4 cv = c4[j];
            const int base = j * 4;
            r += (cv.x > my) || (cv.x == my && (base + 0) < t);
            r += (cv.y > my) || (cv.y == my && (base + 1) < t);
            r += (cv.z > my) || (cv.z == my && (base + 2) < t);
            r += (cv.w > my) || (cv.w == my && (base + 3) < t);
        }
        if (r == pr)       s_c[0] = t;     // big segment of the pair
        if (r == 255 - pr) s_c[1] = t;     // small segment of the pair
    }
    __syncthreads();

    // thread t owns float4 index t of each row; h = (4t) mod 128 ->
    // single W fragment per thread.
    const float4 w4     = ((const float4*)W)[t & 31];
    const float  inv_fm = 1.0f / FM;
    const float  b0     = bias[0];
    const float4* xb    = (const float4*)x + (size_t)b * NF * RQ;

    for (int half = 0; half < 2; ++half) {
        const int c = s_c[half];
        const int m = cnt[c];

        // ---- atomic-cursor compaction of members of c ----
        if (t == 0) s_cur = 0;
        __syncthreads();
#pragma unroll
        for (int k = 0; k < SPT; ++k)
            if (sv[k] == c) list[atomicAdd(&s_cur, 1)] = t * SPT + k;
        __syncthreads();

        // ---- fused stream: 4-row batches, one barrier per batch ----
        float4 a0 = {0,0,0,0};
        float  mx = -INFINITY, denom = 0.f;

        float4 c0 = {0,0,0,0}, c1 = {0,0,0,0}, c2 = {0,0,0,0}, c3 = {0,0,0,0};
        if (m > 0) c0 = xb[(size_t)list[0] * RQ + t];
        if (m > 1) c1 = xb[(size_t)list[1] * RQ + t];
        if (m > 2) c2 = xb[(size_t)list[2] * RQ + t];
        if (m > 3) c3 = xb[(size_t)list[3] * RQ + t];

        int par = 0;
        for (int r = 0; r < m; r += 4, par ^= 1) {
            // software-pipelined load of the next 4 rows (zeros past end)
            float4 n0 = {0,0,0,0}, n1 = {0,0,0,0}, n2 = {0,0,0,0}, n3 = {0,0,0,0};
            if (r + 4 < m) n0 = xb[(size_t)list[r + 4] * RQ + t];
            if (r + 5 < m) n1 = xb[(size_t)list[r + 5] * RQ + t];
            if (r + 6 < m) n2 = xb[(size_t)list[r + 6] * RQ + t];
            if (r + 7 < m) n3 = xb[(size_t)list[r + 7] * RQ + t];

            // four independent block-wide dots, one barrier
            float p0 = c0.x * w4.x + c0.y * w4.y + c0.z * w4.z + c0.w * w4.w;
            float p1 = c1.x * w4.x + c1.y * w4.y + c1.z * w4.z + c1.w * w4.w;
            float p2 = c2.x * w4.x + c2.y * w4.y + c2.z * w4.z + c2.w * w4.w;
            float p3 = c3.x * w4.x + c3.y * w4.y + c3.z * w4.z + c3.w * w4.w;
#pragma unroll
            for (int off = 32; off >= 1; off >>= 1) {
                p0 += __shfl_xor(p0, off, 64);
                p1 += __shfl_xor(p1, off, 64);
                p2 += __shfl_xor(p2, off, 64);
                p3 += __shfl_xor(p3, off, 64);
            }
            if (lane == 0) red4[par][wid] = make_float4(p0, p1, p2, p3);
            __syncthreads();

            float4 sm = {0,0,0,0};
#pragma unroll
            for (int i = 0; i < 16; ++i) {
                const float4 v = red4[par][i];
                sm.x += v.x; sm.y += v.y; sm.z += v.z; sm.w += v.w;
            }
            const float s0 = sm.x * inv_fm + b0;
            const float s1 = (r + 1 < m) ? (sm.y * inv_fm + b0) : -INFINITY;
            const float s2 = (r + 2 < m) ? (sm.z * inv_fm + b0) : -INFINITY;
            const float s3 = (r + 3 < m) ? (sm.w * inv_fm + b0) : -INFINITY;

            // online softmax accumulate, one rescale-check per batch
            const float m4 = fmaxf(fmaxf(s0, s1), fmaxf(s2, s3));
            if (m4 > mx) {
                const float sc = __expf(mx - m4);   // exp(-inf)=0 on first batch
                denom *= sc;
                a0.x *= sc; a0.y *= sc; a0.z *= sc; a0.w *= sc;
                mx = m4;
            }
            const float e0 = __expf(s0 - mx);
            const float e1 = (r + 1 < m) ? __expf(s1 - mx) : 0.f;
            const float e2 = (r + 2 < m) ? __expf(s2 - mx) : 0.f;
            const float e3 = (r + 3 < m) ? __expf(s3 - mx) : 0.f;
            denom += (e0 + e1) + (e2 + e3);
            a0.x += e0 * c0.x + e1 * c1.x + e2 * c2.x + e3 * c3.x;
            a0.y += e0 * c0.y + e1 * c1.y + e2 * c2.y + e3 * c3.y;
            a0.z += e0 * c0.z + e1 * c1.z + e2 * c2.z + e3 * c3.z;
            a0.w += e0 * c0.w + e1 * c1.w + e2 * c2.w + e3 * c3.w;

            c0 = n0; c1 = n1; c2 = n2; c3 = n3;
        }

        // ---- normalize + write ----
        const float inv = (denom > 0.f) ? (1.0f / denom) : 0.f;
        float4* op = (float4*)(out + (size_t)(b * NC + c) * ROW);
        a0.x *= inv; a0.y *= inv; a0.z *= inv; a0.w *= inv;
        op[t] = a0;

        __syncthreads();   // protect list/s_cur/red4 reuse in second half
    }
}

// ---------------------------------------------------------------------------
extern "C" void kernel_launch(void* const* d_in, const int* in_sizes, int n_in,
                              void* d_out, int out_size, void* d_ws, size_t ws_size,
                              hipStream_t stream) {
    const float* x    = (const float*)d_in[0];
    const float* W    = (const float*)d_in[1];
    const float* bias = (const float*)d_in[2];
    const int*   seg  = (const int*)d_in[3];
    float*       out  = (float*)d_out;

    k_fused<<<(NC / 2) * B, NT, 0, stream>>>(x, W, bias, seg, out);
}

// Round 11
// 53.865 us; speedup vs baseline: 1.8053x; 1.8053x over previous
//
#include <hip/hip_runtime.h>
#include <math.h>

#define B   4
#define NF  4096
#define FM  32
#define H   128
#define NC  256
#define ROW (FM * H)      // 4096 floats per (b,n) row
#define RQ  (ROW / 4)     // 1024 float4 per row
#define NT  1024          // threads per block (16 waves)
#define SPT (NF / NT)     // 4 seg values per thread

// One kernel. Block = (pair_rank, b), 1024 threads; processes segments
// ord[pr] and ord[255-pr] (folded size-pairing -> near-constant work).
// 512 blocks = 2 blocks/CU = 32 waves/CU (VGPR<=64 via one float4/row/thread
// and launch_bounds(1024,8) — round 10 showed 2 float4/row spills and costs
// 2x; do NOT widen the batch). Preamble per block (seg tiny/L2-resident):
// histogram, rank by size, atomic-cursor compaction. Stream: 2-row batches,
// one barrier per batch, online softmax; every x element read exactly once.
__global__ __launch_bounds__(NT, 8) void k_fused(const float* __restrict__ x,
                                                 const float* __restrict__ W,
                                                 const float* __restrict__ bias,
                                                 const int* __restrict__ seg,
                                                 float* __restrict__ out) {
    __shared__ __align__(16) int cnt[NC];
    __shared__ int   list[NF];       // 16 KB member list of current segment
    __shared__ float redA[32];       // 16 wave sums x 2 parity slots
    __shared__ float redB[32];
    __shared__ int   s_c[2];
    __shared__ int   s_cur;

    const int t    = threadIdx.x;
    const int wid  = t >> 6;         // 0..15
    const int lane = t & 63;
    const int pr   = blockIdx.x >> 2;     // pair rank 0..127
    const int b    = blockIdx.x & 3;

    // ---- histogram of segment sizes (thread t owns ints [4t, 4t+4)) ----
    int sv[SPT];
    if (t < NC) cnt[t] = 0;
    __syncthreads();
    {
        const int4 v = ((const int4*)seg)[t];
        sv[0] = v.x; sv[1] = v.y; sv[2] = v.z; sv[3] = v.w;
#pragma unroll
        for (int k = 0; k < SPT; ++k)
            atomicAdd(&cnt[sv[k]], 1);
    }
    __syncthreads();

    // ---- rank segment t (t<256) by descending count, ties by id ----
    if (t < NC) {
        const int my = cnt[t];
        int r = 0;
        const int4* c4 = (const int4*)cnt;   // broadcast reads
#pragma unroll 16
        for (int j = 0; j < 64; ++j) {
            const int4 cv = c4[j];
            const int base = j * 4;
            r += (cv.x > my) || (cv.x == my && (base + 0) < t);
            r += (cv.y > my) || (cv.y == my && (base + 1) < t);
            r += (cv.z > my) || (cv.z == my && (base + 2) < t);
            r += (cv.w > my) || (cv.w == my && (base + 3) < t);
        }
        if (r == pr)       s_c[0] = t;     // big segment of the pair
        if (r == 255 - pr) s_c[1] = t;     // small segment of the pair
    }
    __syncthreads();

    // thread t owns float4 index t of each row; h = (4t) mod 128 ->
    // single W fragment per thread.
    const float4 w4     = ((const float4*)W)[t & 31];
    const float  inv_fm = 1.0f / FM;
    const float  b0     = bias[0];
    const float4* xb    = (const float4*)x + (size_t)b * NF * RQ;

    for (int half = 0; half < 2; ++half) {
        const int c = s_c[half];
        const int m = cnt[c];

        // ---- atomic-cursor compaction of members of c ----
        if (t == 0) s_cur = 0;
        __syncthreads();
#pragma unroll
        for (int k = 0; k < SPT; ++k)
            if (sv[k] == c) list[atomicAdd(&s_cur, 1)] = t * SPT + k;
        __syncthreads();

        // ---- fused stream: 2-row batches, one barrier per batch ----
        float4 a0 = {0,0,0,0};
        float  mx = -INFINITY, denom = 0.f;

        float4 c0 = {0,0,0,0}, d0 = {0,0,0,0};
        if (m > 0) c0 = *(xb + (size_t)list[0] * RQ + t);
        if (m > 1) d0 = *(xb + (size_t)list[1] * RQ + t);

        int par = 0;
        for (int r = 0; r < m; r += 2, par ^= 1) {
            // software-pipelined load of the next two rows
            float4 n0, n2;
            const bool h2 = (r + 1 < m);
            const bool h3 = (r + 2 < m);
            const bool h4 = (r + 3 < m);
            if (h3) n0 = *(xb + (size_t)list[r + 2] * RQ + t);
            if (h4) n2 = *(xb + (size_t)list[r + 3] * RQ + t);

            // two independent block-wide dots, one barrier
            float p0 = c0.x * w4.x + c0.y * w4.y + c0.z * w4.z + c0.w * w4.w;
            float p1 = d0.x * w4.x + d0.y * w4.y + d0.z * w4.z + d0.w * w4.w;
#pragma unroll
            for (int off = 32; off >= 1; off >>= 1) {
                p0 += __shfl_xor(p0, off, 64);
                p1 += __shfl_xor(p1, off, 64);
            }
            if (lane == 0) { redA[par * 16 + wid] = p0; redB[par * 16 + wid] = p1; }
            __syncthreads();
            float s0 = 0.f, s1 = 0.f;
#pragma unroll
            for (int i = 0; i < 16; ++i) {
                s0 += redA[par * 16 + i];
                s1 += redB[par * 16 + i];
            }
            s0 = s0 * inv_fm + b0;
            s1 = h2 ? (s1 * inv_fm + b0) : -INFINITY;

            // online softmax accumulate, one rescale-check per pair
            const float m2 = fmaxf(s0, s1);
            if (m2 > mx) {
                const float sc = __expf(mx - m2);   // exp(-inf)=0 on first pair
                denom *= sc;
                a0.x *= sc; a0.y *= sc; a0.z *= sc; a0.w *= sc;
                mx = m2;
            }
            const float e0 = __expf(s0 - mx);
            const float e1 = h2 ? __expf(s1 - mx) : 0.f;
            denom += e0 + e1;
            a0.x += e0 * c0.x + e1 * d0.x;
            a0.y += e0 * c0.y + e1 * d0.y;
            a0.z += e0 * c0.z + e1 * d0.z;
            a0.w += e0 * c0.w + e1 * d0.w;

            if (h3) c0 = n0;
            if (h4) d0 = n2;
        }

        // ---- normalize + write ----
        const float inv = (denom > 0.f) ? (1.0f / denom) : 0.f;
        float4* op = (float4*)(out + (size_t)(b * NC + c) * ROW);
        a0.x *= inv; a0.y *= inv; a0.z *= inv; a0.w *= inv;
        op[t] = a0;

        __syncthreads();   // protect list/s_cur/red reuse in second half
    }
}

// ---------------------------------------------------------------------------
extern "C" void kernel_launch(void* const* d_in, const int* in_sizes, int n_in,
                              void* d_out, int out_size, void* d_ws, size_t ws_size,
                              hipStream_t stream) {
    const float* x    = (const float*)d_in[0];
    const float* W    = (const float*)d_in[1];
    const float* bias = (const float*)d_in[2];
    const int*   seg  = (const int*)d_in[3];
    float*       out  = (float*)d_out;

    k_fused<<<(NC / 2) * B, NT, 0, stream>>>(x, W, bias, seg, out);
}